// Round 1
// baseline (119.915 us; speedup 1.0000x reference)
//
#include <hip/hip_runtime.h>
#include <hip/hip_bf16.h>

namespace {

constexpr int kB = 8, kT = 64, kE = 4, kD = 256, kH = 1024;

__device__ __forceinline__ float gelu_exact(float v) {
  return 0.5f * v * (1.0f + erff(v * 0.70710678118654752f));
}

__global__ __launch_bounds__(256, 1)
void moe_ffn_kernel(const float* __restrict__ x,
                    const float* __restrict__ fc1,
                    const float* __restrict__ b1,
                    const float* __restrict__ fc2,
                    const float* __restrict__ b2,
                    const float* __restrict__ Wr,
                    const float* __restrict__ br,
                    float* __restrict__ out) {
  __shared__ float xs[kB][kD];        // 8 KB
  __shared__ float hid[kB][kH];       // 32 KB
  __shared__ float red[4][kB][kD];    // 32 KB
  __shared__ float gates_s[kB];

  const int tid = threadIdx.x;
  const int bid = blockIdx.x;     // == t*kE + e
  const int t  = bid >> 2;
  const int te = bid;

  // ---- phase 0: stage x[b, t, :] into LDS (coalesced per b-row) ----
#pragma unroll
  for (int b = 0; b < kB; ++b)
    xs[b][tid] = x[((size_t)b * kT + t) * kD + tid];
  __syncthreads();

  // ---- router gates: wave w handles b = w and b = w+4 ----
  const int wave = tid >> 6, lane = tid & 63;
  {
    const float* __restrict__ wr = Wr + (size_t)te * kD;
    const float w0 = wr[lane], w1 = wr[lane + 64], w2 = wr[lane + 128], w3 = wr[lane + 192];
#pragma unroll
    for (int bb = 0; bb < 2; ++bb) {
      const int b = wave + bb * 4;
      float p = xs[b][lane] * w0 + xs[b][lane + 64] * w1 +
                xs[b][lane + 128] * w2 + xs[b][lane + 192] * w3;
#pragma unroll
      for (int off = 32; off; off >>= 1) p += __shfl_xor(p, off);
      if (lane == 0) {
        const float g = p + br[te];
        gates_s[b] = g > 0.0f ? g : 0.0f;
      }
    }
  }

  // ---- phase 1: hidden[b][h] = gelu(x . fc1 + b1); thread owns h = tid*4..+3 ----
  {
    const float4* __restrict__ w =
        reinterpret_cast<const float4*>(fc1 + (size_t)te * kD * kH);  // [D][H/4]
    float4 acc[kB];
#pragma unroll
    for (int b = 0; b < kB; ++b) acc[b] = make_float4(0.f, 0.f, 0.f, 0.f);
#pragma unroll 4
    for (int d = 0; d < kD; ++d) {
      const float4 wv = w[d * (kH / 4) + tid];
#pragma unroll
      for (int b = 0; b < kB; ++b) {
        const float xv = xs[b][d];
        acc[b].x = fmaf(xv, wv.x, acc[b].x);
        acc[b].y = fmaf(xv, wv.y, acc[b].y);
        acc[b].z = fmaf(xv, wv.z, acc[b].z);
        acc[b].w = fmaf(xv, wv.w, acc[b].w);
      }
    }
    const float4 bias = reinterpret_cast<const float4*>(b1 + (size_t)te * kH)[tid];
#pragma unroll
    for (int b = 0; b < kB; ++b) {
      float4 v = acc[b];
      v.x = gelu_exact(v.x + bias.x);
      v.y = gelu_exact(v.y + bias.y);
      v.z = gelu_exact(v.z + bias.z);
      v.w = gelu_exact(v.w + bias.w);
      reinterpret_cast<float4*>(&hid[b][0])[tid] = v;
    }
  }
  __syncthreads();

  // ---- phase 2: expert_out partials; wave hg owns 256 h, lane owns float4 of d ----
  {
    const int d4 = tid & 63;    // d = d4*4 .. +3
    const int hg = tid >> 6;    // h-group == wave index
    const float4* __restrict__ w =
        reinterpret_cast<const float4*>(fc2 + (size_t)te * kH * kD);  // [H][D/4]
    float4 acc[kB];
#pragma unroll
    for (int b = 0; b < kB; ++b) acc[b] = make_float4(0.f, 0.f, 0.f, 0.f);
    const int h0 = hg * (kH / 4);
#pragma unroll 4
    for (int i = 0; i < kH / 4; ++i) {
      const int h = h0 + i;
      const float4 wv = w[h * (kD / 4) + d4];
#pragma unroll
      for (int b = 0; b < kB; ++b) {
        const float hv = hid[b][h];  // wave-uniform address -> LDS broadcast
        acc[b].x = fmaf(hv, wv.x, acc[b].x);
        acc[b].y = fmaf(hv, wv.y, acc[b].y);
        acc[b].z = fmaf(hv, wv.z, acc[b].z);
        acc[b].w = fmaf(hv, wv.w, acc[b].w);
      }
    }
#pragma unroll
    for (int b = 0; b < kB; ++b)
      reinterpret_cast<float4*>(&red[hg][b][0])[d4] = acc[b];
  }
  __syncthreads();

  // ---- final: reduce 4 h-groups, add b2, scale by gate, accumulate over e ----
  {
    const int d = tid;
    const float bias2 = b2[(size_t)te * kD + d];
#pragma unroll
    for (int b = 0; b < kB; ++b) {
      const float s = red[0][b][d] + red[1][b][d] + red[2][b][d] + red[3][b][d] + bias2;
      atomicAdd(&out[((size_t)b * kT + t) * kD + d], gates_s[b] * s);
    }
    if (tid == 0) {
      float gs = 0.f;
#pragma unroll
      for (int b = 0; b < kB; ++b) gs += gates_s[b];
      atomicAdd(&out[(size_t)kB * kT * kD], 0.01f * gs * (1.0f / (kB * kT)));
    }
  }
}

}  // namespace

extern "C" void kernel_launch(void* const* d_in, const int* in_sizes, int n_in,
                              void* d_out, int out_size, void* d_ws, size_t ws_size,
                              hipStream_t stream) {
  const float* x   = (const float*)d_in[0];
  const float* fc1 = (const float*)d_in[1];
  const float* b1  = (const float*)d_in[2];
  const float* fc2 = (const float*)d_in[3];
  const float* b2  = (const float*)d_in[4];
  const float* Wr  = (const float*)d_in[5];
  const float* br  = (const float*)d_in[6];
  float* out = (float*)d_out;

  // Zero the accumulation target every call (replays must be deterministic;
  // harness does not re-poison between graph replays).
  hipMemsetAsync(d_out, 0, (size_t)out_size * sizeof(float), stream);

  moe_ffn_kernel<<<dim3(kT * kE), dim3(256), 0, stream>>>(x, fc1, b1, fc2, b2, Wr, br, out);
}

// Round 2
// 104.634 us; speedup vs baseline: 1.1460x; 1.1460x over previous
//
#include <hip/hip_runtime.h>
#include <hip/hip_bf16.h>

namespace {

constexpr int kB = 8, kT = 64, kE = 4, kD = 256, kH = 1024;
constexpr int kNC = 4;            // H-chunks per (t,e)
constexpr int kHc = kH / kNC;     // 256

__device__ __forceinline__ float gelu_exact(float v) {
  return 0.5f * v * (1.0f + erff(v * 0.70710678118654752f));
}

__global__ __launch_bounds__(256, 4)
void moe_ffn_kernel(const float* __restrict__ x,
                    const float* __restrict__ fc1,
                    const float* __restrict__ b1,
                    const float* __restrict__ fc2,
                    const float* __restrict__ b2,
                    const float* __restrict__ Wr,
                    const float* __restrict__ br,
                    float* __restrict__ out) {
  __shared__ float xs[kB][kD];     // 8 KB
  __shared__ float hid[kB][kHc];   // 8 KB
  __shared__ float gates_s[kB];

  const int tid = threadIdx.x;
  const int bid = blockIdx.x;      // te * kNC + c
  const int te  = bid / kNC;       // 0..255 == t*kE + e
  const int c   = bid % kNC;       // h-chunk
  const int t   = te >> 2;
  const int h0  = c * kHc;

  // ---- stage x[b, t, :] into LDS ----
#pragma unroll
  for (int b = 0; b < kB; ++b)
    xs[b][tid] = x[((size_t)b * kT + t) * kD + tid];
  __syncthreads();

  const int wave = tid >> 6, lane = tid & 63;

  // ---- router gates (computed redundantly per chunk; cheap) ----
  {
    const float* __restrict__ wr = Wr + (size_t)te * kD;
    const float w0 = wr[lane], w1 = wr[lane + 64], w2 = wr[lane + 128], w3 = wr[lane + 192];
#pragma unroll
    for (int bb = 0; bb < 2; ++bb) {
      const int b = wave + bb * 4;
      float p = xs[b][lane] * w0 + xs[b][lane + 64] * w1 +
                xs[b][lane + 128] * w2 + xs[b][lane + 192] * w3;
#pragma unroll
      for (int off = 32; off; off >>= 1) p += __shfl_xor(p, off);
      if (lane == 0) {
        const float g = p + br[te];
        gates_s[b] = g > 0.0f ? g : 0.0f;
      }
    }
  }

  // ---- phase 1: hid[b][tid] = gelu(x . fc1[:, h0+tid] + b1) ----
  {
    const float* __restrict__ w = fc1 + (size_t)te * kD * kH + h0 + tid;
    float acc[kB] = {0.f, 0.f, 0.f, 0.f, 0.f, 0.f, 0.f, 0.f};
#pragma unroll 8
    for (int d = 0; d < kD; ++d) {
      const float wv = w[(size_t)d * kH];   // wave reads 256 B contiguous
#pragma unroll
      for (int b = 0; b < kB; ++b) acc[b] = fmaf(xs[b][d], wv, acc[b]);
    }
    const float bias = b1[(size_t)te * kH + h0 + tid];
#pragma unroll
    for (int b = 0; b < kB; ++b) hid[b][tid] = gelu_exact(acc[b] + bias);
  }
  __syncthreads();   // covers hid and gates_s

  // ---- phase 2: thread owns d = tid; sum over chunk's h; no cross-wave reduce ----
  {
    const float* __restrict__ w = fc2 + (size_t)te * kH * kD + (size_t)h0 * kD + tid;
    float acc[kB] = {0.f, 0.f, 0.f, 0.f, 0.f, 0.f, 0.f, 0.f};
#pragma unroll 8
    for (int i = 0; i < kHc; ++i) {
      const float wv = w[(size_t)i * kD];   // wave reads 256 B contiguous
#pragma unroll
      for (int b = 0; b < kB; ++b) acc[b] = fmaf(hid[b][i], wv, acc[b]);
    }
    const float bias2 = (c == 0) ? b2[(size_t)te * kD + tid] : 0.f;
#pragma unroll
    for (int b = 0; b < kB; ++b)
      atomicAdd(&out[((size_t)b * kT + t) * kD + tid], gates_s[b] * (acc[b] + bias2));

    if (c == 0 && tid == 0) {
      float gs = 0.f;
#pragma unroll
      for (int b = 0; b < kB; ++b) gs += gates_s[b];
      atomicAdd(&out[(size_t)kB * kT * kD], 0.01f * gs * (1.0f / (kB * kT)));
    }
  }
}

}  // namespace

extern "C" void kernel_launch(void* const* d_in, const int* in_sizes, int n_in,
                              void* d_out, int out_size, void* d_ws, size_t ws_size,
                              hipStream_t stream) {
  const float* x   = (const float*)d_in[0];
  const float* fc1 = (const float*)d_in[1];
  const float* b1  = (const float*)d_in[2];
  const float* fc2 = (const float*)d_in[3];
  const float* b2  = (const float*)d_in[4];
  const float* Wr  = (const float*)d_in[5];
  const float* br  = (const float*)d_in[6];
  float* out = (float*)d_out;

  // Zero the accumulation target every call (graph replays must be
  // deterministic; harness does not re-poison between replays).
  hipMemsetAsync(d_out, 0, (size_t)out_size * sizeof(float), stream);

  moe_ffn_kernel<<<dim3(kT * kE * kNC), dim3(256), 0, stream>>>(x, fc1, b1, fc2, b2, Wr, br, out);
}